// Round 3
// baseline (116.372 us; speedup 1.0000x reference)
//
#include <hip/hip_runtime.h>

#define IN_F 4096
#define OUT_F 16384
#define M_ROWS 512

#define BM 256
#define BN 128
#define BK 64
#define NKT (IN_F / BK)  // 64
#define THREADS 512

typedef __bf16 bf16x8_t __attribute__((ext_vector_type(8)));
typedef float f32x4_t __attribute__((ext_vector_type(4)));
typedef int i32x4_t __attribute__((ext_vector_type(4)));

__device__ __forceinline__ void gld16(const void* g, void* l) {
    __builtin_amdgcn_global_load_lds(
        (const __attribute__((address_space(1))) void*)g,
        (__attribute__((address_space(3))) void*)l,
        16 /*bytes, literal*/, 0, 0);
}

// ---------------- pre-pass: x fp32 -> bf16, inverse-swizzled tile layout ----------------
// Tile t = mt*64+kt is the exact linear byte image global_load_lds drops into LDS.
// GEMM reads elem (row,col) at LDS byte (row*128 + col*2) ^ ((row&7)<<4), so linear
// slot (row, rem) holds x[row][col = rem ^ ((row&7)<<3)].
__global__ __launch_bounds__(256)
void xpack_kernel(const float* __restrict__ x, __bf16* __restrict__ xp) {
    const int tid = blockIdx.x * 256 + (int)threadIdx.x;
    const int e0 = tid * 8;
    const int tile = e0 >> 14;
    const int within = e0 & 16383;
    const int row = within >> 6;
    const int rem0 = within & 63;
    const int mt = tile >> 6;
    const int kt = tile & 63;
    const int grow = mt * 256 + row;
    const int gcol = kt * 64 + (rem0 ^ ((row & 7) << 3));
    const float* src = x + (size_t)grow * IN_F + gcol;
    f32x4_t a = *(const f32x4_t*)(src);
    f32x4_t b = *(const f32x4_t*)(src + 4);
    bf16x8_t o;
    o[0] = (__bf16)a[0]; o[1] = (__bf16)a[1]; o[2] = (__bf16)a[2]; o[3] = (__bf16)a[3];
    o[4] = (__bf16)b[0]; o[5] = (__bf16)b[1]; o[6] = (__bf16)b[2]; o[7] = (__bf16)b[3];
    *(bf16x8_t*)(xp + e0) = o;
}

// ---------------- main GEMM: 1 barrier/kt, counted vmcnt, phase-split MFMA ----------------
__global__ __launch_bounds__(THREADS, 2)
void qgemm3_kernel(const __bf16* __restrict__ xp, const int* __restrict__ Wq,
                   const float* __restrict__ scales, const float* __restrict__ bias,
                   float* __restrict__ out) {
    __shared__ __align__(16) unsigned char sA[2][BM * BK * 2];  // 2 x 32 KB
    __shared__ __align__(16) unsigned char sB[2][BN * BK * 2];  // 2 x 16 KB

    const int bid = (int)blockIdx.x;
    const int g = (bid & 7) * 32 + (bid >> 3);  // XCD swizzle (256 % 8 == 0, bijective)
    const int mt = g & 1;                       // mt inner: mt-pair lands on same XCD -> Wq L2 hit
    const int nt = g >> 1;
    const int brow = mt * BM;
    const int bcol = nt * BN;

    const int t = (int)threadIdx.x;
    const int lane = t & 63;
    const int wid = t >> 6;    // 8 waves
    const int wr = wid >> 1;   // 0..3
    const int wc = wid & 1;    // 0..1

    // ---- B staging: 128x64 int32 -> per thread 16 int32 (rows rB, rB+64; 8 cols) ----
    const int rB = t >> 3;            // 0..63
    const int cB = (t & 7) * 8;       // int32 col
    const int* wg = Wq + (size_t)(bcol + rB) * IN_F + cB;
    const int offB = rB * 128 + ((cB * 2) ^ ((rB & 7) << 4));  // byte; row rB+64 => +8192 (same XOR)

    // ---- A via global_load_lds from pre-swizzled ws ----
    const __bf16* xt = xp + (size_t)(mt * NKT) * (BM * BK) + t * 8;
    const int ldsAoff = wid * 1024;  // wave-uniform; HW adds lane*16

    f32x4_t acc[4][4];
#pragma unroll
    for (int i = 0; i < 4; ++i)
#pragma unroll
        for (int j = 0; j < 4; ++j) {
            f32x4_t z = {0.f, 0.f, 0.f, 0.f};
            acc[i][j] = z;
        }

    const int arow = wr * 64 + (lane & 15);
    const int browf = wc * 64 + (lane & 15);
    const int kb = (lane >> 4) * 16;  // byte offset of lane's 8 bf16 in k

    i32x4_t bvA[4], bvB[4];
    bf16x8_t af[2][4], bf[2][4];

#define ISSUE_A(KT1, PB)                                              \
    do {                                                              \
        const __bf16* s_ = xt + (size_t)(KT1) * (BM * BK);            \
        unsigned char* d_ = &sA[PB][0] + ldsAoff;                     \
        gld16(s_, d_);                                                \
        gld16(s_ + 4096, d_ + 8192);                                  \
        gld16(s_ + 8192, d_ + 16384);                                 \
        gld16(s_ + 12288, d_ + 24576);                                \
    } while (0)

#define ISSUE_B(KT2, BV)                                              \
    do {                                                              \
        const int* p_ = wg + (size_t)(KT2) * BK;                      \
        BV[0] = *(const i32x4_t*)(p_);                                \
        BV[1] = *(const i32x4_t*)(p_ + 4);                            \
        BV[2] = *(const i32x4_t*)(p_ + (size_t)64 * IN_F);            \
        BV[3] = *(const i32x4_t*)(p_ + (size_t)64 * IN_F + 4);        \
    } while (0)

#define WRITE_B(BV, PB)                                               \
    do {                                                              \
        bf16x8_t w0_, w1_;                                            \
        _Pragma("unroll") for (int j_ = 0; j_ < 4; ++j_) {            \
            w0_[j_] = (__bf16)(float)BV[0][j_];                       \
            w0_[4 + j_] = (__bf16)(float)BV[1][j_];                   \
            w1_[j_] = (__bf16)(float)BV[2][j_];                       \
            w1_[4 + j_] = (__bf16)(float)BV[3][j_];                   \
        }                                                             \
        *(bf16x8_t*)(&sB[PB][0] + offB) = w0_;                        \
        *(bf16x8_t*)(&sB[PB][0] + offB + 8192) = w1_;                 \
    } while (0)

#define READ_FRAGS(CUR)                                                              \
    do {                                                                             \
        _Pragma("unroll") for (int m_ = 0; m_ < 4; ++m_) {                           \
            const int r_ = arow + m_ * 16;                                           \
            const int x_ = (r_ & 7) << 4;                                            \
            af[0][m_] = *(const bf16x8_t*)(&sA[CUR][0] + r_ * 128 + ((kb) ^ x_));    \
            af[1][m_] = *(const bf16x8_t*)(&sA[CUR][0] + r_ * 128 + ((64 + kb) ^ x_)); \
        }                                                                            \
        _Pragma("unroll") for (int n_ = 0; n_ < 4; ++n_) {                           \
            const int r_ = browf + n_ * 16;                                          \
            const int x_ = (r_ & 7) << 4;                                            \
            bf[0][n_] = *(const bf16x8_t*)(&sB[CUR][0] + r_ * 128 + ((kb) ^ x_));    \
            bf[1][n_] = *(const bf16x8_t*)(&sB[CUR][0] + r_ * 128 + ((64 + kb) ^ x_)); \
        }                                                                            \
    } while (0)

#define MFMA_KS(KS)                                                       \
    do {                                                                  \
        _Pragma("unroll") for (int m_ = 0; m_ < 4; ++m_)                  \
            _Pragma("unroll") for (int n_ = 0; n_ < 4; ++n_)              \
                acc[m_][n_] = __builtin_amdgcn_mfma_f32_16x16x32_bf16(    \
                    af[KS][m_], bf[KS][n_], acc[m_][n_], 0, 0, 0);        \
    } while (0)

// One barrier per kt. Entry wait: vmcnt(4) retires this kt's A-DMA (issued before
// last kt's B-globals, in-order retirement); lgkmcnt(0) publishes last kt's B writes.
#define KT_STEP(CUR, KT, BVW, BVI)                                        \
    do {                                                                  \
        asm volatile("s_waitcnt vmcnt(4) lgkmcnt(0)" ::: "memory");       \
        __builtin_amdgcn_s_barrier();                                     \
        __builtin_amdgcn_sched_barrier(0);                                \
        READ_FRAGS(CUR);                                                  \
        {                                                                 \
            const int k1_ = ((KT) + 1 < NKT) ? (KT) + 1 : NKT - 1;        \
            ISSUE_A(k1_, (CUR) ^ 1);                                      \
        }                                                                 \
        __builtin_amdgcn_sched_barrier(0);                                \
        __builtin_amdgcn_s_setprio(1);                                    \
        MFMA_KS(0);                                                       \
        __builtin_amdgcn_s_setprio(0);                                    \
        WRITE_B(BVW, (CUR) ^ 1);                                          \
        {                                                                 \
            const int k2_ = ((KT) + 2 < NKT) ? (KT) + 2 : NKT - 1;        \
            ISSUE_B(k2_, BVI);                                            \
        }                                                                 \
        __builtin_amdgcn_s_setprio(1);                                    \
        MFMA_KS(1);                                                       \
        __builtin_amdgcn_s_setprio(0);                                    \
    } while (0)

    // -------- prologue --------
    ISSUE_A(0, 0);
    ISSUE_B(0, bvA);
    asm volatile("s_waitcnt vmcnt(0)" ::: "memory");
    WRITE_B(bvA, 0);
    ISSUE_B(1, bvB);

#pragma unroll 1
    for (int kt = 0; kt < NKT; kt += 2) {
        KT_STEP(0, kt, bvB, bvA);
        KT_STEP(1, kt + 1, bvA, bvB);
    }

    // -------- epilogue: per-col dequant scale + bias, fp32 store --------
    // C/D layout: col = lane&15, row = (lane>>4)*4 + reg  (m89-verified)
    const int orow = brow + wr * 64 + ((lane >> 4) << 2);
    const int ocol = bcol + wc * 64 + (lane & 15);
#pragma unroll
    for (int n = 0; n < 4; ++n) {
        const int c = ocol + n * 16;
        const float sc = scales[c];
        const float bs = bias[c];
#pragma unroll
        for (int m = 0; m < 4; ++m) {
            const int r = orow + m * 16;
            float* po = out + (size_t)r * OUT_F + c;
#pragma unroll
            for (int j = 0; j < 4; ++j) {
                po[(size_t)j * OUT_F] = acc[m][n][j] * sc + bs;
            }
        }
    }
#undef ISSUE_A
#undef ISSUE_B
#undef WRITE_B
#undef READ_FRAGS
#undef MFMA_KS
#undef KT_STEP
}

// ---------------- fallback (no workspace): round-1 kernel, known-correct ----------------
__global__ __launch_bounds__(256, 2)
void qgemm_fallback(const float* __restrict__ x, const int* __restrict__ Wq,
                    const float* __restrict__ scales, const float* __restrict__ bias,
                    float* __restrict__ out) {
    __shared__ __align__(16) unsigned char fA[128 * 64 * 2];
    __shared__ __align__(16) unsigned char fB[128 * 64 * 2];

    const int bid = (int)blockIdx.x;
    const int g = (bid & 7) * 64 + (bid >> 3);
    const int mt = g & 3;
    const int nt = g >> 2;
    const int brow = mt * 128;
    const int bcol = nt * 128;

    const int t = (int)threadIdx.x;
    const int lane = t & 63;
    const int wid = t >> 6;
    const int wr = wid >> 1;
    const int wc = wid & 1;

    const int srow = t >> 4;
    const int sc4 = t & 15;

    const float* xg = x + (size_t)(brow + srow) * IN_F + sc4 * 4;
    const int* wg = Wq + (size_t)(bcol + srow) * IN_F + sc4 * 4;

    f32x4_t acc[4][4];
#pragma unroll
    for (int i = 0; i < 4; ++i)
#pragma unroll
        for (int j = 0; j < 4; ++j) {
            f32x4_t z = {0.f, 0.f, 0.f, 0.f};
            acc[i][j] = z;
        }

    const int frow_a = wr * 64 + (lane & 15);
    const int frow_b = wc * 64 + (lane & 15);
    const int fk = (lane >> 4) * 16;

#pragma unroll 1
    for (int kt = 0; kt < IN_F / 64; ++kt) {
        const int k0 = kt * 64;
        f32x4_t av[8];
        i32x4_t bv[8];
#pragma unroll
        for (int i = 0; i < 8; ++i) {
            av[i] = *(const f32x4_t*)(xg + k0 + (size_t)i * 16 * IN_F);
            bv[i] = *(const i32x4_t*)(wg + k0 + (size_t)i * 16 * IN_F);
        }
        __syncthreads();
#pragma unroll
        for (int i = 0; i < 8; ++i) {
            const int row = srow + i * 16;
            unsigned off = (unsigned)(row * 128 + sc4 * 8);
            off ^= (unsigned)(row & 7) << 4;
            __bf16 pa[4], pb[4];
#pragma unroll
            for (int j = 0; j < 4; ++j) {
                pa[j] = (__bf16)av[i][j];
                pb[j] = (__bf16)(float)bv[i][j];
            }
            *(unsigned long long*)(fA + off) = *(unsigned long long*)pa;
            *(unsigned long long*)(fB + off) = *(unsigned long long*)pb;
        }
        __syncthreads();
#pragma unroll
        for (int ks = 0; ks < 2; ++ks) {
            bf16x8_t afv[4], bfv[4];
#pragma unroll
            for (int m = 0; m < 4; ++m) {
                const int row = frow_a + m * 16;
                afv[m] = *(const bf16x8_t*)(fA + (row * 128 + ((ks * 64 + fk) ^ ((row & 7) << 4))));
            }
#pragma unroll
            for (int n = 0; n < 4; ++n) {
                const int row = frow_b + n * 16;
                bfv[n] = *(const bf16x8_t*)(fB + (row * 128 + ((ks * 64 + fk) ^ ((row & 7) << 4))));
            }
#pragma unroll
            for (int m = 0; m < 4; ++m)
#pragma unroll
                for (int n = 0; n < 4; ++n)
                    acc[m][n] = __builtin_amdgcn_mfma_f32_16x16x32_bf16(
                        afv[m], bfv[n], acc[m][n], 0, 0, 0);
        }
    }

    const int orow = brow + wr * 64 + ((lane >> 4) << 2);
    const int ocol = bcol + wc * 64 + (lane & 15);
#pragma unroll
    for (int n = 0; n < 4; ++n) {
        const int c = ocol + n * 16;
        const float sc = scales[c];
        const float bs = bias[c];
#pragma unroll
        for (int m = 0; m < 4; ++m) {
            const int r = orow + m * 16;
            float* po = out + (size_t)r * OUT_F + c;
#pragma unroll
            for (int j = 0; j < 4; ++j) {
                po[(size_t)j * OUT_F] = acc[m][n][j] * sc + bs;
            }
        }
    }
}

extern "C" void kernel_launch(void* const* d_in, const int* in_sizes, int n_in,
                              void* d_out, int out_size, void* d_ws, size_t ws_size,
                              hipStream_t stream) {
    const float* x = (const float*)d_in[0];
    const int* Wq = (const int*)d_in[1];
    const float* scales = (const float*)d_in[2];
    const float* bias = (const float*)d_in[3];
    float* out = (float*)d_out;

    const size_t xp_bytes = (size_t)M_ROWS * IN_F * 2;  // 4 MB
    const bool pre = (ws_size >= xp_bytes) && (d_ws != nullptr);

    if (pre) {
        __bf16* xp = (__bf16*)d_ws;
        xpack_kernel<<<dim3((M_ROWS * IN_F / 8) / 256), dim3(256), 0, stream>>>(x, xp);
        qgemm3_kernel<<<dim3(256), dim3(THREADS), 0, stream>>>(xp, Wq, scales, bias, out);
    } else {
        qgemm_fallback<<<dim3(512), dim3(256), 0, stream>>>(x, Wq, scales, bias, out);
    }
}